// Round 6
// baseline (261.874 us; speedup 1.0000x reference)
//
#include <hip/hip_runtime.h>
#include <hip/hip_bf16.h>

#define B_ROWS 65536
#define KNUM 20
#define ZROW 5000   // extra all-zero row appended to ekb (masked-gather target)

typedef short  bfrag8 __attribute__((ext_vector_type(8)));  // 8 bf16 (4 VGPRs)
typedef float  facc4  __attribute__((ext_vector_type(4)));  // 4 fp32 acc

__device__ __forceinline__ unsigned short f2bf(float f) {
    union { float f; unsigned u; } x; x.f = f;
    unsigned r = (x.u + 0x7FFFu + ((x.u >> 16) & 1u)) >> 16;   // RNE
    return (unsigned short)r;
}
__device__ __forceinline__ float bf2f(unsigned s) {
    union { unsigned u; float f; } x; x.u = s << 16; return x.f;
}

// ---------------------------------------------------------------------------
// Prepack (every call): weights -> bf16 transposed [N][K]; emb_k -> bf16 with
// one extra zeroed row at index ZROW (masked gathers redirect there).
//   WT1: 114688 ush | WT2: 32768 | WT3: 8192 | ekb: 320064 (5001 rows)
// ---------------------------------------------------------------------------
__global__ __launch_bounds__(256) void prepack(
    const float* __restrict__ W1, const float* __restrict__ W2,
    const float* __restrict__ W3, const float* __restrict__ ek,
    unsigned short* __restrict__ WT1, unsigned short* __restrict__ WT2,
    unsigned short* __restrict__ WT3, unsigned short* __restrict__ ekb)
{
    const int i = blockIdx.x * 256 + threadIdx.x;
    if (i < 114688) {                 // WT1[n*448+k] = bf16(W1[k*256+n])
        const int n = i / 448, k = i % 448;
        WT1[i] = f2bf(W1[k * 256 + n]);
    } else if (i < 147456) {          // WT2[n*256+k] = bf16(W2[k*128+n])
        const int j = i - 114688;
        const int n = j >> 8, k = j & 255;
        WT2[j] = f2bf(W2[k * 128 + n]);
    } else if (i < 155648) {          // WT3[n*128+k] = bf16(W3[k*64+n])
        const int j = i - 147456;
        const int n = j >> 7, k = j & 127;
        WT3[j] = f2bf(W3[k * 64 + n]);
    } else if (i < 475712) {          // ekb = bf16(ek) + zero row at ZROW
        const int j = i - 155648;
        ekb[j] = (j < 320000) ? f2bf(ek[j]) : (unsigned short)0;
    }
}

// ---------------------------------------------------------------------------
// Fused KDMLP, one block = 32 rows, 256 threads = 4 waves.
// LDS (29696 B -> 5 blocks/CU, 20 waves/CU):
//   [0, 29184)  : Xs[32][456] ushort (gather out / GEMM1 A-src)
//                 then H1s[32][264] at 0 (..16896), H2s[32][136] at 16896
//                 (..25600) — inside the dead Xs region.
//   [29184, 29696): tmp[32][4] float (final cross-wave reduce)
// Gathers use SCALAR addressing: readfirstlane forces r/u/itm/valid/kk into
// SGPRs -> idx fetches are s_loads, gather bases are SALU; per-gather VALU is
// just v_lshl (bf16->f32) + v_add. Masking = redirect to ekb's zero row via
// s_cselect (no cndmask, loads stay independent & unrolled).
// B-operands stream from prepacked WT* in L2 (no LDS staging / K-loop barriers).
// ---------------------------------------------------------------------------
__global__ __launch_bounds__(256, 5) void kdmlp_fused(
    const int* __restrict__ user, const int* __restrict__ item,
    const int* __restrict__ pk, const int* __restrict__ tk, const int* __restrict__ ik,
    const int* __restrict__ vp, const int* __restrict__ vt, const int* __restrict__ vi,
    const float* __restrict__ eu, const float* __restrict__ ei,
    const unsigned short* __restrict__ WT1, const unsigned short* __restrict__ WT2,
    const unsigned short* __restrict__ WT3, const unsigned short* __restrict__ ekb,
    const float* __restrict__ b1, const float* __restrict__ b2,
    const float* __restrict__ b3, const float* __restrict__ Wp,
    const float* __restrict__ bp, float* __restrict__ out)
{
    __shared__ char smem[29696];
    unsigned short* Xs  = (unsigned short*)smem;            // stride 456
    unsigned short* H1s = (unsigned short*)smem;            // stride 264
    unsigned short* H2s = (unsigned short*)(smem + 16896);  // stride 136
    float (*tmp)[4]     = (float(*)[4])(smem + 29184);

    const int tid  = threadIdx.x;
    const int lane = tid & 63;
    const int wid  = tid >> 6;          // 0..3
    const int lm   = lane & 15;
    const int quad = lane >> 4;
    const int m0   = blockIdx.x * 32;

    // ================= phase 0: gather + masked means -> Xs =================
    #pragma unroll
    for (int lr = 0; lr < 8; ++lr) {
        const int rl = wid * 8 + lr;    // local row 0..31
        const int r  = __builtin_amdgcn_readfirstlane(m0 + rl);
        const int u   = __builtin_amdgcn_readfirstlane(user[r]);
        const int itm = __builtin_amdgcn_readfirstlane(item[r]);
        float2 a = *(const float2*)(eu + (size_t)u   * 128 + 2 * lane);
        float2 b = *(const float2*)(ei + (size_t)itm * 128 + 2 * lane);
        ushort2 pa; pa.x = f2bf(a.x); pa.y = f2bf(a.y);
        ushort2 pb; pb.x = f2bf(b.x); pb.y = f2bf(b.y);
        *(ushort2*)(Xs + rl * 456 + 2 * lane)       = pa;
        *(ushort2*)(Xs + rl * 456 + 128 + 2 * lane) = pb;

        const int* bases[3]  = { pk, tk, ik };
        const int* vbases[3] = { vp, vt, vi };
        #pragma unroll
        for (int s = 0; s < 3; ++s) {
            const int valid = __builtin_amdgcn_readfirstlane(vbases[s][r]);
            const int* prow = bases[s] + r * KNUM;
            float acc = 0.f;
            #pragma unroll
            for (int j = 0; j < KNUM; ++j) {
                int kk = __builtin_amdgcn_readfirstlane(prow[j]);   // s_load
                kk = (j < valid) ? kk : ZROW;                       // s_cselect
                acc += bf2f(ekb[(size_t)kk * 64 + lane]);           // saddr load
            }
            const float mean = (valid > 0) ? acc / (float)valid : 0.f;
            Xs[rl * 456 + 256 + s * 64 + lane] = f2bf(mean);
        }
    }
    __syncthreads();

    // ================= GEMM1: [32,448] @ W1 -> H1 [32,256] ==================
    // wave wid covers cols wid*64..+64 (nt 0..3), rows mt 0..1.
    facc4 acc1[2][4];
    #pragma unroll
    for (int mt = 0; mt < 2; ++mt)
        #pragma unroll
        for (int nt = 0; nt < 4; ++nt)
            acc1[mt][nt] = (facc4){0.f, 0.f, 0.f, 0.f};

    #pragma unroll
    for (int ks = 0; ks < 14; ++ks) {           // K = 448 = 14 * 32
        bfrag8 af[2], bfv[4];
        #pragma unroll
        for (int mt = 0; mt < 2; ++mt)
            af[mt] = *(const bfrag8*)(Xs + (mt * 16 + lm) * 456 + ks * 32 + quad * 8);
        #pragma unroll
        for (int nt = 0; nt < 4; ++nt)
            bfv[nt] = *(const bfrag8*)(WT1 + (size_t)(wid * 64 + nt * 16 + lm) * 448
                                           + ks * 32 + quad * 8);
        #pragma unroll
        for (int mt = 0; mt < 2; ++mt)
            #pragma unroll
            for (int nt = 0; nt < 4; ++nt)
                acc1[mt][nt] = __builtin_amdgcn_mfma_f32_16x16x32_bf16(
                    af[mt], bfv[nt], acc1[mt][nt], 0, 0, 0);
    }
    __syncthreads();                            // all Xs reads done

    // epilogue 1 -> H1s (C/D: col=lane&15 base, row=quad*4+reg; r3-verified)
    #pragma unroll
    for (int nt = 0; nt < 4; ++nt) {
        const int col = wid * 64 + nt * 16 + lm;
        const float bias = b1[col];
        #pragma unroll
        for (int mt = 0; mt < 2; ++mt)
            #pragma unroll
            for (int i = 0; i < 4; ++i) {
                const int row = mt * 16 + quad * 4 + i;
                H1s[row * 264 + col] = f2bf(fmaxf(acc1[mt][nt][i] + bias, 0.f));
            }
    }
    __syncthreads();

    // ================= GEMM2: [32,256] @ W2 -> H2 [32,128] ==================
    facc4 acc2[2][2];
    #pragma unroll
    for (int mt = 0; mt < 2; ++mt)
        #pragma unroll
        for (int nt = 0; nt < 2; ++nt)
            acc2[mt][nt] = (facc4){0.f, 0.f, 0.f, 0.f};

    #pragma unroll
    for (int ks = 0; ks < 8; ++ks) {            // K = 256 = 8 * 32
        bfrag8 af[2], bfv[2];
        #pragma unroll
        for (int mt = 0; mt < 2; ++mt)
            af[mt] = *(const bfrag8*)(H1s + (mt * 16 + lm) * 264 + ks * 32 + quad * 8);
        #pragma unroll
        for (int nt = 0; nt < 2; ++nt)
            bfv[nt] = *(const bfrag8*)(WT2 + (size_t)(wid * 32 + nt * 16 + lm) * 256
                                           + ks * 32 + quad * 8);
        #pragma unroll
        for (int mt = 0; mt < 2; ++mt)
            #pragma unroll
            for (int nt = 0; nt < 2; ++nt)
                acc2[mt][nt] = __builtin_amdgcn_mfma_f32_16x16x32_bf16(
                    af[mt], bfv[nt], acc2[mt][nt], 0, 0, 0);
    }
    // epilogue 2 -> H2s (region disjoint from H1s reads; barrier only after)
    #pragma unroll
    for (int nt = 0; nt < 2; ++nt) {
        const int col = wid * 32 + nt * 16 + lm;
        const float bias = b2[col];
        #pragma unroll
        for (int mt = 0; mt < 2; ++mt)
            #pragma unroll
            for (int i = 0; i < 4; ++i) {
                const int row = mt * 16 + quad * 4 + i;
                H2s[row * 136 + col] = f2bf(fmaxf(acc2[mt][nt][i] + bias, 0.f));
            }
    }
    __syncthreads();

    // ========= GEMM3: [32,128] @ W3 -> relu -> dot Wp, fused reduce =========
    // all 4 waves: cols wid*16..+16, rows mt 0..1.
    {
        facc4 acc3[2];
        #pragma unroll
        for (int mt = 0; mt < 2; ++mt) acc3[mt] = (facc4){0.f, 0.f, 0.f, 0.f};

        const int col3 = wid * 16 + lm;
        #pragma unroll
        for (int ks = 0; ks < 4; ++ks) {        // K = 128 = 4 * 32
            bfrag8 af[2];
            #pragma unroll
            for (int mt = 0; mt < 2; ++mt)
                af[mt] = *(const bfrag8*)(H2s + (mt * 16 + lm) * 136 + ks * 32 + quad * 8);
            bfrag8 bfv = *(const bfrag8*)(WT3 + (size_t)col3 * 128 + ks * 32 + quad * 8);
            #pragma unroll
            for (int mt = 0; mt < 2; ++mt)
                acc3[mt] = __builtin_amdgcn_mfma_f32_16x16x32_bf16(af[mt], bfv, acc3[mt], 0, 0, 0);
        }
        const float bias = b3[col3];
        const float wpv  = Wp[col3];
        #pragma unroll
        for (int mt = 0; mt < 2; ++mt)
            #pragma unroll
            for (int i = 0; i < 4; ++i) {
                float p = fmaxf(acc3[mt][i] + bias, 0.f) * wpv;
                p += __shfl_xor(p, 1);
                p += __shfl_xor(p, 2);
                p += __shfl_xor(p, 4);
                p += __shfl_xor(p, 8);          // sum over the 16 cols (lm)
                if (lm == 0) tmp[mt * 16 + quad * 4 + i][wid] = p;
            }
    }
    __syncthreads();

    if (tid < 32)
        out[m0 + tid] = tmp[tid][0] + tmp[tid][1] + tmp[tid][2] + tmp[tid][3] + bp[0];
}

// ---------------------------------------------------------------------------
extern "C" void kernel_launch(void* const* d_in, const int* in_sizes, int n_in,
                              void* d_out, int out_size, void* d_ws, size_t ws_size,
                              hipStream_t stream) {
    (void)in_sizes; (void)n_in; (void)out_size; (void)ws_size;

    const int*   user = (const int*)d_in[0];
    const int*   item = (const int*)d_in[1];
    const int*   pk   = (const int*)d_in[2];
    const int*   tk   = (const int*)d_in[3];
    const int*   ik   = (const int*)d_in[4];
    const int*   vp   = (const int*)d_in[5];
    const int*   vt   = (const int*)d_in[6];
    const int*   vi   = (const int*)d_in[7];
    const float* eu   = (const float*)d_in[8];
    const float* ei   = (const float*)d_in[9];
    const float* ek   = (const float*)d_in[10];
    const float* W1   = (const float*)d_in[11];
    const float* b1   = (const float*)d_in[12];
    const float* W2   = (const float*)d_in[13];
    const float* b2   = (const float*)d_in[14];
    const float* W3   = (const float*)d_in[15];
    const float* b3   = (const float*)d_in[16];
    const float* Wp   = (const float*)d_in[17];
    const float* bp   = (const float*)d_in[18];
    float* out = (float*)d_out;

    // ws: prepacked bf16 weights + emb_k(+zero row) (~951 KB)
    unsigned short* WT1 = (unsigned short*)d_ws;
    unsigned short* WT2 = WT1 + 114688;
    unsigned short* WT3 = WT2 + 32768;
    unsigned short* ekb = WT3 + 8192;      // 320064 ushorts (5001 rows x 64)

    prepack<<<1859, 256, 0, stream>>>(W1, W2, W3, ek, WT1, WT2, WT3, ekb);

    kdmlp_fused<<<B_ROWS / 32, 256, 0, stream>>>(
        user, item, pk, tk, ik, vp, vt, vi, eu, ei,
        WT1, WT2, WT3, ekb, b1, b2, b3, Wp, bp, out);
}

// Round 7
// 235.873 us; speedup vs baseline: 1.1102x; 1.1102x over previous
//
#include <hip/hip_runtime.h>
#include <hip/hip_bf16.h>

#define B_ROWS 65536
#define KNUM 20
#define ZROW 5000   // extra all-zero row appended to ekb (masked-gather target)

typedef short  bfrag8 __attribute__((ext_vector_type(8)));  // 8 bf16 (4 VGPRs)
typedef float  facc4  __attribute__((ext_vector_type(4)));  // 4 fp32 acc

__device__ __forceinline__ unsigned short f2bf(float f) {
    union { float f; unsigned u; } x; x.f = f;
    unsigned r = (x.u + 0x7FFFu + ((x.u >> 16) & 1u)) >> 16;   // RNE
    return (unsigned short)r;
}
__device__ __forceinline__ float bf2f(unsigned s) {
    union { unsigned u; float f; } x; x.u = s << 16; return x.f;
}

// ---------------------------------------------------------------------------
// Prepack (every call): weights -> bf16 transposed [N][K]; emb_k -> bf16 with
// one extra zeroed row at index ZROW (masked gathers redirect there).
//   WT1: 114688 ush | WT2: 32768 | WT3: 8192 | ekb: 320064 (5001 rows)
// ---------------------------------------------------------------------------
__global__ __launch_bounds__(256) void prepack(
    const float* __restrict__ W1, const float* __restrict__ W2,
    const float* __restrict__ W3, const float* __restrict__ ek,
    unsigned short* __restrict__ WT1, unsigned short* __restrict__ WT2,
    unsigned short* __restrict__ WT3, unsigned short* __restrict__ ekb)
{
    const int i = blockIdx.x * 256 + threadIdx.x;
    if (i < 114688) {                 // WT1[n*448+k] = bf16(W1[k*256+n])
        const int n = i / 448, k = i % 448;
        WT1[i] = f2bf(W1[k * 256 + n]);
    } else if (i < 147456) {          // WT2[n*256+k] = bf16(W2[k*128+n])
        const int j = i - 114688;
        const int n = j >> 8, k = j & 255;
        WT2[j] = f2bf(W2[k * 128 + n]);
    } else if (i < 155648) {          // WT3[n*128+k] = bf16(W3[k*64+n])
        const int j = i - 147456;
        const int n = j >> 7, k = j & 127;
        WT3[j] = f2bf(W3[k * 64 + n]);
    } else if (i < 475712) {          // ekb = bf16(ek) + zero row at ZROW
        const int j = i - 155648;
        ekb[j] = (j < 320000) ? f2bf(ek[j]) : (unsigned short)0;
    }
}

// ---------------------------------------------------------------------------
// Fused KDMLP, one block = 64 rows, 512 threads = 8 waves (2 blocks/CU).
// LDS 59392 B:
//   [0, 58368)  : Xs[64][456] ushort -> then H1s[64][264] at 0 (..33792),
//                 H2s[64][136] at 33792 (..51200) in the dead Xs region.
//   [58368, 59392): tmp[64][4] float (final cross-wave reduce)
// Scalar gather (r6-verified): s_load indices, zero-row redirect, saddr loads.
// B-operands stream from prepacked WT* in L2 with EARLY ISSUE before each
// barrier (barrier drains vmcnt -> B is resident when consumed) and a
// register ping-pong prefetch inside the K-loops.
// ---------------------------------------------------------------------------
__global__ __launch_bounds__(512, 4) void kdmlp_fused(
    const int* __restrict__ user, const int* __restrict__ item,
    const int* __restrict__ pk, const int* __restrict__ tk, const int* __restrict__ ik,
    const int* __restrict__ vp, const int* __restrict__ vt, const int* __restrict__ vi,
    const float* __restrict__ eu, const float* __restrict__ ei,
    const unsigned short* __restrict__ WT1, const unsigned short* __restrict__ WT2,
    const unsigned short* __restrict__ WT3, const unsigned short* __restrict__ ekb,
    const float* __restrict__ b1, const float* __restrict__ b2,
    const float* __restrict__ b3, const float* __restrict__ Wp,
    const float* __restrict__ bp, float* __restrict__ out)
{
    __shared__ char smem[59392];
    unsigned short* Xs  = (unsigned short*)smem;            // stride 456
    unsigned short* H1s = (unsigned short*)smem;            // stride 264
    unsigned short* H2s = (unsigned short*)(smem + 33792);  // stride 136
    float (*tmp)[4]     = (float(*)[4])(smem + 58368);

    const int tid  = threadIdx.x;
    const int lane = tid & 63;
    const int wid  = tid >> 6;          // 0..7
    const int lm   = lane & 15;
    const int quad = lane >> 4;
    const int m0   = blockIdx.x * 64;

    // ---- early issue: GEMM1 B (ks=0); completes during gather ----
    bfrag8 g1b0[2], g1b1[2];
    #pragma unroll
    for (int nt = 0; nt < 2; ++nt)
        g1b0[nt] = *(const bfrag8*)(WT1 + (size_t)(wid * 32 + nt * 16 + lm) * 448
                                        + quad * 8);

    // ================= phase 0: scalar gather -> Xs =================
    #pragma unroll
    for (int lr = 0; lr < 8; ++lr) {
        const int rl = wid * 8 + lr;    // local row 0..63
        const int r  = __builtin_amdgcn_readfirstlane(m0 + rl);
        const int u   = __builtin_amdgcn_readfirstlane(user[r]);
        const int itm = __builtin_amdgcn_readfirstlane(item[r]);
        float2 a = *(const float2*)(eu + (size_t)u   * 128 + 2 * lane);
        float2 b = *(const float2*)(ei + (size_t)itm * 128 + 2 * lane);
        ushort2 pa; pa.x = f2bf(a.x); pa.y = f2bf(a.y);
        ushort2 pb; pb.x = f2bf(b.x); pb.y = f2bf(b.y);
        *(ushort2*)(Xs + rl * 456 + 2 * lane)       = pa;
        *(ushort2*)(Xs + rl * 456 + 128 + 2 * lane) = pb;

        const int* bases[3]  = { pk, tk, ik };
        const int* vbases[3] = { vp, vt, vi };
        #pragma unroll
        for (int s = 0; s < 3; ++s) {
            const int valid = __builtin_amdgcn_readfirstlane(vbases[s][r]);
            const int* prow = bases[s] + r * KNUM;
            float acc = 0.f;
            #pragma unroll
            for (int j = 0; j < KNUM; ++j) {
                int kk = __builtin_amdgcn_readfirstlane(prow[j]);   // s_load
                kk = (j < valid) ? kk : ZROW;                       // s_cselect
                acc += bf2f(ekb[(size_t)kk * 64 + lane]);           // saddr load
            }
            const float mean = (valid > 0) ? acc / (float)valid : 0.f;
            Xs[rl * 456 + 256 + s * 64 + lane] = f2bf(mean);
        }
    }
    __syncthreads();                    // drains vmcnt -> g1b0 resident

    // ================= GEMM1: [64,448] @ W1 -> H1 [64,256] ==================
    // wave wid: cols wid*32..+32 (nt 0..1), rows mt 0..3. Ping-pong B prefetch.
    facc4 acc1[4][2];
    #pragma unroll
    for (int mt = 0; mt < 4; ++mt)
        #pragma unroll
        for (int nt = 0; nt < 2; ++nt)
            acc1[mt][nt] = (facc4){0.f, 0.f, 0.f, 0.f};

    #pragma unroll
    for (int kp = 0; kp < 7; ++kp) {            // K = 448 = 7 * (2*32)
        const int ksA = 2 * kp, ksB = 2 * kp + 1;
        #pragma unroll
        for (int nt = 0; nt < 2; ++nt)          // prefetch ksB
            g1b1[nt] = *(const bfrag8*)(WT1 + (size_t)(wid * 32 + nt * 16 + lm) * 448
                                            + ksB * 32 + quad * 8);
        bfrag8 af[4];
        #pragma unroll
        for (int mt = 0; mt < 4; ++mt)
            af[mt] = *(const bfrag8*)(Xs + (mt * 16 + lm) * 456 + ksA * 32 + quad * 8);
        #pragma unroll
        for (int mt = 0; mt < 4; ++mt)
            #pragma unroll
            for (int nt = 0; nt < 2; ++nt)
                acc1[mt][nt] = __builtin_amdgcn_mfma_f32_16x16x32_bf16(
                    af[mt], g1b0[nt], acc1[mt][nt], 0, 0, 0);
        if (kp < 6) {
            #pragma unroll
            for (int nt = 0; nt < 2; ++nt)      // prefetch next pair's ksA
                g1b0[nt] = *(const bfrag8*)(WT1 + (size_t)(wid * 32 + nt * 16 + lm) * 448
                                                + (ksB + 1) * 32 + quad * 8);
        }
        #pragma unroll
        for (int mt = 0; mt < 4; ++mt)
            af[mt] = *(const bfrag8*)(Xs + (mt * 16 + lm) * 456 + ksB * 32 + quad * 8);
        #pragma unroll
        for (int mt = 0; mt < 4; ++mt)
            #pragma unroll
            for (int nt = 0; nt < 2; ++nt)
                acc1[mt][nt] = __builtin_amdgcn_mfma_f32_16x16x32_bf16(
                    af[mt], g1b1[nt], acc1[mt][nt], 0, 0, 0);
    }

    // ---- early issue: GEMM2 B (ks=0); completes by next barrier ----
    const int colw = wid * 16 + lm;             // this wave's col in GEMM2/H2
    bfrag8 g2b0 = *(const bfrag8*)(WT2 + (size_t)colw * 256 + quad * 8);
    bfrag8 g2b1;

    __syncthreads();                            // all Xs reads done

    // epilogue 1 -> H1s (C/D: col=lane&15 base, row=quad*4+reg; r3-verified)
    #pragma unroll
    for (int nt = 0; nt < 2; ++nt) {
        const int col = wid * 32 + nt * 16 + lm;
        const float bias = b1[col];
        #pragma unroll
        for (int mt = 0; mt < 4; ++mt)
            #pragma unroll
            for (int i = 0; i < 4; ++i) {
                const int row = mt * 16 + quad * 4 + i;
                H1s[row * 264 + col] = f2bf(fmaxf(acc1[mt][nt][i] + bias, 0.f));
            }
    }
    __syncthreads();

    // ================= GEMM2: [64,256] @ W2 -> H2 [64,128] ==================
    // wave wid: 16 cols (colw), rows mt 0..3. Ping-pong B prefetch.
    facc4 acc2[4];
    #pragma unroll
    for (int mt = 0; mt < 4; ++mt) acc2[mt] = (facc4){0.f, 0.f, 0.f, 0.f};

    #pragma unroll
    for (int kp = 0; kp < 4; ++kp) {            // K = 256 = 4 * (2*32)
        const int ksA = 2 * kp, ksB = 2 * kp + 1;
        g2b1 = *(const bfrag8*)(WT2 + (size_t)colw * 256 + ksB * 32 + quad * 8);
        bfrag8 af[4];
        #pragma unroll
        for (int mt = 0; mt < 4; ++mt)
            af[mt] = *(const bfrag8*)(H1s + (mt * 16 + lm) * 264 + ksA * 32 + quad * 8);
        #pragma unroll
        for (int mt = 0; mt < 4; ++mt)
            acc2[mt] = __builtin_amdgcn_mfma_f32_16x16x32_bf16(af[mt], g2b0, acc2[mt], 0, 0, 0);
        if (kp < 3)
            g2b0 = *(const bfrag8*)(WT2 + (size_t)colw * 256 + (ksB + 1) * 32 + quad * 8);
        #pragma unroll
        for (int mt = 0; mt < 4; ++mt)
            af[mt] = *(const bfrag8*)(H1s + (mt * 16 + lm) * 264 + ksB * 32 + quad * 8);
        #pragma unroll
        for (int mt = 0; mt < 4; ++mt)
            acc2[mt] = __builtin_amdgcn_mfma_f32_16x16x32_bf16(af[mt], g2b1, acc2[mt], 0, 0, 0);
    }

    // ---- early issue: GEMM3 B (all 4 ks); completes by next barrier ----
    // GEMM3 split: wave-pair w = wid&3 -> cols w*16..+16; mgrp = wid>>2 ->
    // m-tiles {mgrp*2, mgrp*2+1} (rows mgrp*32..+32).
    const int w3   = wid & 3;
    const int mgrp = wid >> 2;
    const int col3 = w3 * 16 + lm;
    bfrag8 g3b[4];
    #pragma unroll
    for (int ks = 0; ks < 4; ++ks)
        g3b[ks] = *(const bfrag8*)(WT3 + (size_t)col3 * 128 + ks * 32 + quad * 8);

    // epilogue 2 -> H2s (disjoint from H1s reads; barrier only after)
    {
        const float bias = b2[colw];
        #pragma unroll
        for (int mt = 0; mt < 4; ++mt)
            #pragma unroll
            for (int i = 0; i < 4; ++i) {
                const int row = mt * 16 + quad * 4 + i;
                H2s[row * 136 + colw] = f2bf(fmaxf(acc2[mt][i] + bias, 0.f));
            }
    }
    __syncthreads();

    // ========= GEMM3: [64,128] @ W3 -> relu -> dot Wp, fused reduce =========
    {
        facc4 acc3[2];
        #pragma unroll
        for (int mtl = 0; mtl < 2; ++mtl) acc3[mtl] = (facc4){0.f, 0.f, 0.f, 0.f};

        #pragma unroll
        for (int ks = 0; ks < 4; ++ks) {        // K = 128 = 4 * 32
            bfrag8 af[2];
            #pragma unroll
            for (int mtl = 0; mtl < 2; ++mtl)
                af[mtl] = *(const bfrag8*)(H2s + (mgrp * 32 + mtl * 16 + lm) * 136
                                               + ks * 32 + quad * 8);
            #pragma unroll
            for (int mtl = 0; mtl < 2; ++mtl)
                acc3[mtl] = __builtin_amdgcn_mfma_f32_16x16x32_bf16(
                    af[mtl], g3b[ks], acc3[mtl], 0, 0, 0);
        }
        const float bias = b3[col3];
        const float wpv  = Wp[col3];
        #pragma unroll
        for (int mtl = 0; mtl < 2; ++mtl)
            #pragma unroll
            for (int i = 0; i < 4; ++i) {
                float p = fmaxf(acc3[mtl][i] + bias, 0.f) * wpv;
                p += __shfl_xor(p, 1);
                p += __shfl_xor(p, 2);
                p += __shfl_xor(p, 4);
                p += __shfl_xor(p, 8);          // sum over the 16 cols (lm)
                if (lm == 0) tmp[mgrp * 32 + mtl * 16 + quad * 4 + i][w3] = p;
            }
    }
    __syncthreads();

    if (tid < 64)
        out[m0 + tid] = tmp[tid][0] + tmp[tid][1] + tmp[tid][2] + tmp[tid][3] + bp[0];
}

// ---------------------------------------------------------------------------
extern "C" void kernel_launch(void* const* d_in, const int* in_sizes, int n_in,
                              void* d_out, int out_size, void* d_ws, size_t ws_size,
                              hipStream_t stream) {
    (void)in_sizes; (void)n_in; (void)out_size; (void)ws_size;

    const int*   user = (const int*)d_in[0];
    const int*   item = (const int*)d_in[1];
    const int*   pk   = (const int*)d_in[2];
    const int*   tk   = (const int*)d_in[3];
    const int*   ik   = (const int*)d_in[4];
    const int*   vp   = (const int*)d_in[5];
    const int*   vt   = (const int*)d_in[6];
    const int*   vi   = (const int*)d_in[7];
    const float* eu   = (const float*)d_in[8];
    const float* ei   = (const float*)d_in[9];
    const float* ek   = (const float*)d_in[10];
    const float* W1   = (const float*)d_in[11];
    const float* b1   = (const float*)d_in[12];
    const float* W2   = (const float*)d_in[13];
    const float* b2   = (const float*)d_in[14];
    const float* W3   = (const float*)d_in[15];
    const float* b3   = (const float*)d_in[16];
    const float* Wp   = (const float*)d_in[17];
    const float* bp   = (const float*)d_in[18];
    float* out = (float*)d_out;

    // ws: prepacked bf16 weights + emb_k(+zero row) (~951 KB)
    unsigned short* WT1 = (unsigned short*)d_ws;
    unsigned short* WT2 = WT1 + 114688;
    unsigned short* WT3 = WT2 + 32768;
    unsigned short* ekb = WT3 + 8192;      // 320064 ushorts (5001 rows x 64)

    prepack<<<1859, 256, 0, stream>>>(W1, W2, W3, ek, WT1, WT2, WT3, ekb);

    kdmlp_fused<<<B_ROWS / 64, 512, 0, stream>>>(
        user, item, pk, tk, ik, vp, vt, vi, eu, ei,
        WT1, WT2, WT3, ekb, b1, b2, b3, Wp, bp, out);
}

// Round 8
// 227.551 us; speedup vs baseline: 1.1508x; 1.0366x over previous
//
#include <hip/hip_runtime.h>
#include <hip/hip_bf16.h>

#define B_ROWS 65536
#define KNUM 20
#define ZROW 5000   // extra all-zero row appended to ekb (masked-gather target)

typedef short  bfrag8 __attribute__((ext_vector_type(8)));  // 8 bf16 (4 VGPRs)
typedef float  facc4  __attribute__((ext_vector_type(4)));  // 4 fp32 acc

__device__ __forceinline__ unsigned short f2bf(float f) {
    union { float f; unsigned u; } x; x.f = f;
    unsigned r = (x.u + 0x7FFFu + ((x.u >> 16) & 1u)) >> 16;   // RNE
    return (unsigned short)r;
}
__device__ __forceinline__ float bf2f(unsigned s) {
    union { unsigned u; float f; } x; x.u = s << 16; return x.f;
}

// ---------------------------------------------------------------------------
// Prepack (every call): weights -> bf16 transposed [N][K]; emb_k -> bf16 with
// one extra zeroed row at index ZROW (masked gathers redirect there).
//   WT1: 114688 ush | WT2: 32768 | WT3: 8192 | ekb: 320064 (5001 rows)
// ---------------------------------------------------------------------------
__global__ __launch_bounds__(256) void prepack(
    const float* __restrict__ W1, const float* __restrict__ W2,
    const float* __restrict__ W3, const float* __restrict__ ek,
    unsigned short* __restrict__ WT1, unsigned short* __restrict__ WT2,
    unsigned short* __restrict__ WT3, unsigned short* __restrict__ ekb)
{
    const int i = blockIdx.x * 256 + threadIdx.x;
    if (i < 114688) {                 // WT1[n*448+k] = bf16(W1[k*256+n])
        const int n = i / 448, k = i % 448;
        WT1[i] = f2bf(W1[k * 256 + n]);
    } else if (i < 147456) {          // WT2[n*256+k] = bf16(W2[k*128+n])
        const int j = i - 114688;
        const int n = j >> 8, k = j & 255;
        WT2[j] = f2bf(W2[k * 128 + n]);
    } else if (i < 155648) {          // WT3[n*128+k] = bf16(W3[k*64+n])
        const int j = i - 147456;
        const int n = j >> 7, k = j & 127;
        WT3[j] = f2bf(W3[k * 64 + n]);
    } else if (i < 475712) {          // ekb = bf16(ek) + zero row at ZROW
        const int j = i - 155648;
        ekb[j] = (j < 320000) ? f2bf(ek[j]) : (unsigned short)0;
    }
}

// ---------------------------------------------------------------------------
// Fused KDMLP, one block = 64 rows, 512 threads = 8 waves (2 blocks/CU).
// LDS 59392 B:
//   [0, 58368)  : Xs[64][456] ushort -> then H1s[64][264] at 0 (..33792),
//                 H2s[64][136] at 33792 (..51200) in the dead Xs region.
//   [58368, 59392): tmp[64][4] float (final cross-wave reduce)
// Gather (r8): per row ONE coalesced vector load fetches all 60 indices
// (lanes 0-19 pk / 20-39 tk / 40-59 ik); all 8 rows' index vectors issued
// up-front (latency overlapped); indices reach SGPRs via v_readlane (no
// memory, no SQC); mask = s_cselect to ekb's zero row; ekb loads issue
// back-to-back from SALU addresses. user/item/valid stay readfirstlane
// s_loads (contiguous addresses -> SQC-cached).
// B-operands stream from prepacked WT* in L2 with early issue before each
// barrier + register ping-pong prefetch in the K-loops (r7-verified).
// ---------------------------------------------------------------------------
__global__ __launch_bounds__(512, 4) void kdmlp_fused(
    const int* __restrict__ user, const int* __restrict__ item,
    const int* __restrict__ pk, const int* __restrict__ tk, const int* __restrict__ ik,
    const int* __restrict__ vp, const int* __restrict__ vt, const int* __restrict__ vi,
    const float* __restrict__ eu, const float* __restrict__ ei,
    const unsigned short* __restrict__ WT1, const unsigned short* __restrict__ WT2,
    const unsigned short* __restrict__ WT3, const unsigned short* __restrict__ ekb,
    const float* __restrict__ b1, const float* __restrict__ b2,
    const float* __restrict__ b3, const float* __restrict__ Wp,
    const float* __restrict__ bp, float* __restrict__ out)
{
    __shared__ char smem[59392];
    unsigned short* Xs  = (unsigned short*)smem;            // stride 456
    unsigned short* H1s = (unsigned short*)smem;            // stride 264
    unsigned short* H2s = (unsigned short*)(smem + 33792);  // stride 136
    float (*tmp)[4]     = (float(*)[4])(smem + 58368);

    const int tid  = threadIdx.x;
    const int lane = tid & 63;
    const int wid  = tid >> 6;          // 0..7
    const int lm   = lane & 15;
    const int quad = lane >> 4;
    const int m0   = blockIdx.x * 64;

    // ---- early issue: GEMM1 B (ks=0); completes during gather ----
    bfrag8 g1b0[2], g1b1[2];
    #pragma unroll
    for (int nt = 0; nt < 2; ++nt)
        g1b0[nt] = *(const bfrag8*)(WT1 + (size_t)(wid * 32 + nt * 16 + lm) * 448
                                        + quad * 8);

    // ---- early issue: all 8 rows' packed index vectors (one load each) ----
    // lane 0..19 -> pk[r][lane], 20..39 -> tk[r][lane-20], 40..59 -> ik[..],
    // 60..63 -> ik[r][19] (dummy, in-bounds).
    const int* basep = (lane < 20) ? pk : (lane < 40) ? tk : ik;
    const int  loff  = (lane < 20) ? lane
                     : (lane < 40) ? lane - 20
                     : (lane < 60) ? lane - 40 : 19;
    int idxv[8];
    #pragma unroll
    for (int lr = 0; lr < 8; ++lr) {
        const int r = m0 + wid * 8 + lr;
        idxv[lr] = basep[(size_t)r * KNUM + loff];
    }

    // ================= phase 0: gather + masked means -> Xs =================
    #pragma unroll
    for (int lr = 0; lr < 8; ++lr) {
        const int rl = wid * 8 + lr;    // local row 0..63
        const int r  = __builtin_amdgcn_readfirstlane(m0 + rl);
        const int u   = __builtin_amdgcn_readfirstlane(user[r]);
        const int itm = __builtin_amdgcn_readfirstlane(item[r]);
        float2 a = *(const float2*)(eu + (size_t)u   * 128 + 2 * lane);
        float2 b = *(const float2*)(ei + (size_t)itm * 128 + 2 * lane);
        ushort2 pa; pa.x = f2bf(a.x); pa.y = f2bf(a.y);
        ushort2 pb; pb.x = f2bf(b.x); pb.y = f2bf(b.y);
        *(ushort2*)(Xs + rl * 456 + 2 * lane)       = pa;
        *(ushort2*)(Xs + rl * 456 + 128 + 2 * lane) = pb;

        const int* vbases[3] = { vp, vt, vi };
        #pragma unroll
        for (int s = 0; s < 3; ++s) {
            const int valid = __builtin_amdgcn_readfirstlane(vbases[s][r]);
            float acc = 0.f;
            #pragma unroll
            for (int j = 0; j < KNUM; ++j) {
                int kk = __builtin_amdgcn_readlane(idxv[lr], s * KNUM + j); // SGPR
                kk = (j < valid) ? kk : ZROW;                   // s_cselect
                acc += bf2f(ekb[(size_t)kk * 64 + lane]);       // saddr load
            }
            const float mean = (valid > 0) ? acc / (float)valid : 0.f;
            Xs[rl * 456 + 256 + s * 64 + lane] = f2bf(mean);
        }
    }
    __syncthreads();                    // drains vmcnt -> g1b0 resident

    // ================= GEMM1: [64,448] @ W1 -> H1 [64,256] ==================
    // wave wid: cols wid*32..+32 (nt 0..1), rows mt 0..3. Ping-pong B prefetch.
    facc4 acc1[4][2];
    #pragma unroll
    for (int mt = 0; mt < 4; ++mt)
        #pragma unroll
        for (int nt = 0; nt < 2; ++nt)
            acc1[mt][nt] = (facc4){0.f, 0.f, 0.f, 0.f};

    #pragma unroll
    for (int kp = 0; kp < 7; ++kp) {            // K = 448 = 7 * (2*32)
        const int ksA = 2 * kp, ksB = 2 * kp + 1;
        #pragma unroll
        for (int nt = 0; nt < 2; ++nt)          // prefetch ksB
            g1b1[nt] = *(const bfrag8*)(WT1 + (size_t)(wid * 32 + nt * 16 + lm) * 448
                                            + ksB * 32 + quad * 8);
        bfrag8 af[4];
        #pragma unroll
        for (int mt = 0; mt < 4; ++mt)
            af[mt] = *(const bfrag8*)(Xs + (mt * 16 + lm) * 456 + ksA * 32 + quad * 8);
        #pragma unroll
        for (int mt = 0; mt < 4; ++mt)
            #pragma unroll
            for (int nt = 0; nt < 2; ++nt)
                acc1[mt][nt] = __builtin_amdgcn_mfma_f32_16x16x32_bf16(
                    af[mt], g1b0[nt], acc1[mt][nt], 0, 0, 0);
        if (kp < 6) {
            #pragma unroll
            for (int nt = 0; nt < 2; ++nt)      // prefetch next pair's ksA
                g1b0[nt] = *(const bfrag8*)(WT1 + (size_t)(wid * 32 + nt * 16 + lm) * 448
                                                + (ksB + 1) * 32 + quad * 8);
        }
        #pragma unroll
        for (int mt = 0; mt < 4; ++mt)
            af[mt] = *(const bfrag8*)(Xs + (mt * 16 + lm) * 456 + ksB * 32 + quad * 8);
        #pragma unroll
        for (int mt = 0; mt < 4; ++mt)
            #pragma unroll
            for (int nt = 0; nt < 2; ++nt)
                acc1[mt][nt] = __builtin_amdgcn_mfma_f32_16x16x32_bf16(
                    af[mt], g1b1[nt], acc1[mt][nt], 0, 0, 0);
    }

    // ---- early issue: GEMM2 B (ks=0); completes by next barrier ----
    const int colw = wid * 16 + lm;             // this wave's col in GEMM2/H2
    bfrag8 g2b0 = *(const bfrag8*)(WT2 + (size_t)colw * 256 + quad * 8);
    bfrag8 g2b1;

    __syncthreads();                            // all Xs reads done

    // epilogue 1 -> H1s (C/D: col=lane&15 base, row=quad*4+reg; r3-verified)
    #pragma unroll
    for (int nt = 0; nt < 2; ++nt) {
        const int col = wid * 32 + nt * 16 + lm;
        const float bias = b1[col];
        #pragma unroll
        for (int mt = 0; mt < 4; ++mt)
            #pragma unroll
            for (int i = 0; i < 4; ++i) {
                const int row = mt * 16 + quad * 4 + i;
                H1s[row * 264 + col] = f2bf(fmaxf(acc1[mt][nt][i] + bias, 0.f));
            }
    }
    __syncthreads();

    // ================= GEMM2: [64,256] @ W2 -> H2 [64,128] ==================
    facc4 acc2[4];
    #pragma unroll
    for (int mt = 0; mt < 4; ++mt) acc2[mt] = (facc4){0.f, 0.f, 0.f, 0.f};

    #pragma unroll
    for (int kp = 0; kp < 4; ++kp) {            // K = 256 = 4 * (2*32)
        const int ksA = 2 * kp, ksB = 2 * kp + 1;
        g2b1 = *(const bfrag8*)(WT2 + (size_t)colw * 256 + ksB * 32 + quad * 8);
        bfrag8 af[4];
        #pragma unroll
        for (int mt = 0; mt < 4; ++mt)
            af[mt] = *(const bfrag8*)(H1s + (mt * 16 + lm) * 264 + ksA * 32 + quad * 8);
        #pragma unroll
        for (int mt = 0; mt < 4; ++mt)
            acc2[mt] = __builtin_amdgcn_mfma_f32_16x16x32_bf16(af[mt], g2b0, acc2[mt], 0, 0, 0);
        if (kp < 3)
            g2b0 = *(const bfrag8*)(WT2 + (size_t)colw * 256 + (ksB + 1) * 32 + quad * 8);
        #pragma unroll
        for (int mt = 0; mt < 4; ++mt)
            af[mt] = *(const bfrag8*)(H1s + (mt * 16 + lm) * 264 + ksB * 32 + quad * 8);
        #pragma unroll
        for (int mt = 0; mt < 4; ++mt)
            acc2[mt] = __builtin_amdgcn_mfma_f32_16x16x32_bf16(af[mt], g2b1, acc2[mt], 0, 0, 0);
    }

    // ---- early issue: GEMM3 B (all 4 ks); completes by next barrier ----
    // GEMM3 split: w3 = wid&3 -> cols w3*16..+16; mgrp = wid>>2 -> m-tiles
    // {mgrp*2, mgrp*2+1} (rows mgrp*32..+32).
    const int w3   = wid & 3;
    const int mgrp = wid >> 2;
    const int col3 = w3 * 16 + lm;
    bfrag8 g3b[4];
    #pragma unroll
    for (int ks = 0; ks < 4; ++ks)
        g3b[ks] = *(const bfrag8*)(WT3 + (size_t)col3 * 128 + ks * 32 + quad * 8);

    // epilogue 2 -> H2s (disjoint from H1s reads; barrier only after)
    {
        const float bias = b2[colw];
        #pragma unroll
        for (int mt = 0; mt < 4; ++mt)
            #pragma unroll
            for (int i = 0; i < 4; ++i) {
                const int row = mt * 16 + quad * 4 + i;
                H2s[row * 136 + colw] = f2bf(fmaxf(acc2[mt][i] + bias, 0.f));
            }
    }
    __syncthreads();

    // ========= GEMM3: [64,128] @ W3 -> relu -> dot Wp, fused reduce =========
    {
        facc4 acc3[2];
        #pragma unroll
        for (int mtl = 0; mtl < 2; ++mtl) acc3[mtl] = (facc4){0.f, 0.f, 0.f, 0.f};

        #pragma unroll
        for (int ks = 0; ks < 4; ++ks) {        // K = 128 = 4 * 32
            bfrag8 af[2];
            #pragma unroll
            for (int mtl = 0; mtl < 2; ++mtl)
                af[mtl] = *(const bfrag8*)(H2s + (mgrp * 32 + mtl * 16 + lm) * 136
                                               + ks * 32 + quad * 8);
            #pragma unroll
            for (int mtl = 0; mtl < 2; ++mtl)
                acc3[mtl] = __builtin_amdgcn_mfma_f32_16x16x32_bf16(
                    af[mtl], g3b[ks], acc3[mtl], 0, 0, 0);
        }
        const float bias = b3[col3];
        const float wpv  = Wp[col3];
        #pragma unroll
        for (int mtl = 0; mtl < 2; ++mtl)
            #pragma unroll
            for (int i = 0; i < 4; ++i) {
                float p = fmaxf(acc3[mtl][i] + bias, 0.f) * wpv;
                p += __shfl_xor(p, 1);
                p += __shfl_xor(p, 2);
                p += __shfl_xor(p, 4);
                p += __shfl_xor(p, 8);          // sum over the 16 cols (lm)
                if (lm == 0) tmp[mgrp * 32 + mtl * 16 + quad * 4 + i][w3] = p;
            }
    }
    __syncthreads();

    if (tid < 64)
        out[m0 + tid] = tmp[tid][0] + tmp[tid][1] + tmp[tid][2] + tmp[tid][3] + bp[0];
}

// ---------------------------------------------------------------------------
extern "C" void kernel_launch(void* const* d_in, const int* in_sizes, int n_in,
                              void* d_out, int out_size, void* d_ws, size_t ws_size,
                              hipStream_t stream) {
    (void)in_sizes; (void)n_in; (void)out_size; (void)ws_size;

    const int*   user = (const int*)d_in[0];
    const int*   item = (const int*)d_in[1];
    const int*   pk   = (const int*)d_in[2];
    const int*   tk   = (const int*)d_in[3];
    const int*   ik   = (const int*)d_in[4];
    const int*   vp   = (const int*)d_in[5];
    const int*   vt   = (const int*)d_in[6];
    const int*   vi   = (const int*)d_in[7];
    const float* eu   = (const float*)d_in[8];
    const float* ei   = (const float*)d_in[9];
    const float* ek   = (const float*)d_in[10];
    const float* W1   = (const float*)d_in[11];
    const float* b1   = (const float*)d_in[12];
    const float* W2   = (const float*)d_in[13];
    const float* b2   = (const float*)d_in[14];
    const float* W3   = (const float*)d_in[15];
    const float* b3   = (const float*)d_in[16];
    const float* Wp   = (const float*)d_in[17];
    const float* bp   = (const float*)d_in[18];
    float* out = (float*)d_out;

    // ws: prepacked bf16 weights + emb_k(+zero row) (~951 KB)
    unsigned short* WT1 = (unsigned short*)d_ws;
    unsigned short* WT2 = WT1 + 114688;
    unsigned short* WT3 = WT2 + 32768;
    unsigned short* ekb = WT3 + 8192;      // 320064 ushorts (5001 rows x 64)

    prepack<<<1859, 256, 0, stream>>>(W1, W2, W3, ek, WT1, WT2, WT3, ekb);

    kdmlp_fused<<<B_ROWS / 64, 512, 0, stream>>>(
        user, item, pk, tk, ik, vp, vt, vi, eu, ei,
        WT1, WT2, WT3, ekb, b1, b2, b3, Wp, bp, out);
}